// Round 1
// baseline (266.407 us; speedup 1.0000x reference)
//
#include <hip/hip_runtime.h>
#include <hip/hip_bf16.h>
#include <cstdint>

typedef _Float16 f16;
typedef _Float16 f16x4 __attribute__((ext_vector_type(4)));
typedef _Float16 f16x8 __attribute__((ext_vector_type(8)));
typedef float f32x4 __attribute__((ext_vector_type(4)));

#define MFMA16(a, b, c) __builtin_amdgcn_mfma_f32_16x16x32_f16((a), (b), (c), 0, 0, 0)

constexpr int BATCH = 16;
constexpr int C     = 256;    // dim
constexpr int HW    = 4096;   // 64*64 spatial
constexpr int DH    = 32;     // qkv_dim
constexpr int MR    = 288;    // 256 q rows + 32 kv rows in fused QKV GEMM
constexpr float EPS = 1e-5f;

// ---- workspace layout (bytes) ----
constexpr size_t OFF_Q  = 0;                                   // f16 [16][256][4096]
constexpr size_t SZ_Q   = (size_t)BATCH * C * HW * 2;
constexpr size_t OFF_KV = OFF_Q + SZ_Q;                        // f32 [16][32][4096]
constexpr size_t SZ_KV  = (size_t)BATCH * DH * HW * 4;
constexpr size_t OFF_W1 = OFF_KV + SZ_KV;                      // f16 [288][256] (BN inv folded)
constexpr size_t SZ_W1  = (size_t)MR * C * 2;
constexpr size_t OFF_B1 = OFF_W1 + SZ_W1;                      // f32 [288]
constexpr size_t OFF_WP = OFF_B1 + 2048;                       // f16 [256][256]
constexpr size_t SZ_WP  = (size_t)C * C * 2;
constexpr size_t OFF_BP = OFF_WP + SZ_WP;                      // f32 [256]
constexpr size_t OFF_RM = OFF_BP + 1024;                       // f32 [512] row max
constexpr size_t OFF_RS = OFF_RM + 2048;                       // f32 [512] row expsum
constexpr size_t OFF_U  = OFF_RS + 2048;                       // f32 [16][32][32] ctx_t
constexpr size_t WS_NEED = OFF_U + (size_t)BATCH * DH * DH * 4; // ~40.4 MB

// ============================================================================
// K0: fold BN (gamma/sqrt(var+eps)) into conv weights; f16 weights, f32 biases
// ============================================================================
__global__ __launch_bounds__(256) void k0_prep(
    const float* __restrict__ Wq,  const float* __restrict__ gq,  const float* __restrict__ bq,
    const float* __restrict__ mq,  const float* __restrict__ vq,
    const float* __restrict__ Wkv, const float* __restrict__ gkv, const float* __restrict__ bkv,
    const float* __restrict__ mkv, const float* __restrict__ vkv,
    const float* __restrict__ Wp,  const float* __restrict__ gp,  const float* __restrict__ bp,
    const float* __restrict__ mp,  const float* __restrict__ vp,
    f16* __restrict__ W1, float* __restrict__ b1, f16* __restrict__ Wp2, float* __restrict__ bp2) {
  int id = blockIdx.x * 256 + threadIdx.x;
  if (id < 65536) {                       // Wq' rows 0..255
    int o = id >> 8, c = id & 255;
    float inv = gq[o] * rsqrtf(vq[o] + EPS);
    W1[o * 256 + c] = (f16)(Wq[o * 256 + c] * inv);
  } else if (id < 73728) {                // Wkv' rows 256..287
    int o = (id - 65536) >> 8, c = id & 255;
    float inv = gkv[o] * rsqrtf(vkv[o] + EPS);
    W1[(256 + o) * 256 + c] = (f16)(Wkv[o * 256 + c] * inv);
  } else if (id < 139264) {               // Wp'
    int o = (id - 73728) >> 8, c = id & 255;
    float inv = gp[o] * rsqrtf(vp[o] + EPS);
    Wp2[o * 256 + c] = (f16)(Wp[o * 256 + c] * inv);
  } else if (id < 139552) {               // bias for QKV GEMM
    int r = id - 139264;
    if (r < 256) { float inv = gq[r] * rsqrtf(vq[r] + EPS);   b1[r] = bq[r] - mq[r] * inv; }
    else { int e = r - 256; float inv = gkv[e] * rsqrtf(vkv[e] + EPS); b1[r] = bkv[e] - mkv[e] * inv; }
  } else if (id < 139808) {               // bias for proj
    int o = id - 139552;
    float inv = gp[o] * rsqrtf(vp[o] + EPS);
    bp2[o] = bp[o] - mp[o] * inv;
  }
}

// ============================================================================
// K1: fused QKV projection. Per batch: D(288x4096) = W1(288x256) * X(256x4096)
// MFMA f16 16x16x32. Block = 256 thr (4 waves, 2x2 over M-half=144 / N-half=32)
// Mtile=288 (full), Ntile=64. q rows -> f16, kv rows -> f32.
// ============================================================================
__global__ __launch_bounds__(256) void k1_qkv(
    const float* __restrict__ X, const f16* __restrict__ W1, const float* __restrict__ b1,
    f16* __restrict__ qo, float* __restrict__ kvo) {
  __shared__ alignas(16) f16 Wa[288 * 40];  // A chunk [288][32], pitch 40 f16
  __shared__ alignas(16) f16 Bt[64 * 40];   // X^T chunk [n=64][k=32], pitch 40 f16

  const int t = threadIdx.x;
  const int n0 = blockIdx.x * 64;
  const int b  = blockIdx.y;
  const float* Xb = X + (size_t)b * C * HW;

  const int lane = t & 63, w = t >> 6;
  const int l15 = lane & 15, quad = lane >> 4;
  const int wm = w & 1, wn = w >> 1;

  f32x4 acc[9][2] = {};

  for (int kc = 0; kc < 8; ++kc) {
    __syncthreads();
    // stage A: W1[:, kc*32 .. +31]  (1152 x 16B units)
    for (int u = t; u < 1152; u += 256) {
      int r = u >> 2, s = u & 3;
      *(f16x8*)&Wa[r * 40 + s * 8] = *(const f16x8*)&W1[r * 256 + kc * 32 + s * 8];
    }
    // stage B: register-transpose X (4 strided coalesced dword loads -> 1 b64 write)
    {
      int n = t & 63, cg = t >> 6;
      const float* Xc = Xb + (size_t)(kc * 32 + cg * 8) * HW + n0 + n;
      for (int it = 0; it < 2; ++it) {
        float x0 = Xc[(it * 4 + 0) * HW];
        float x1 = Xc[(it * 4 + 1) * HW];
        float x2 = Xc[(it * 4 + 2) * HW];
        float x3 = Xc[(it * 4 + 3) * HW];
        f16x4 pk = { (f16)x0, (f16)x1, (f16)x2, (f16)x3 };
        *(f16x4*)&Bt[n * 40 + cg * 8 + it * 4] = pk;
      }
    }
    __syncthreads();

    f16x8 bf0 = *(const f16x8*)&Bt[(wn * 32 + l15) * 40 + quad * 8];
    f16x8 bf1 = *(const f16x8*)&Bt[(wn * 32 + 16 + l15) * 40 + quad * 8];
#pragma unroll
    for (int mf = 0; mf < 9; ++mf) {
      f16x8 af = *(const f16x8*)&Wa[(wm * 144 + mf * 16 + l15) * 40 + quad * 8];
      acc[mf][0] = MFMA16(af, bf0, acc[mf][0]);
      acc[mf][1] = MFMA16(af, bf1, acc[mf][1]);
    }
  }

  // epilogue: +bias, split q (f16) / kv (f32)
#pragma unroll
  for (int mf = 0; mf < 9; ++mf) {
#pragma unroll
    for (int nf = 0; nf < 2; ++nf) {
      int n = n0 + wn * 32 + nf * 16 + l15;
#pragma unroll
      for (int r = 0; r < 4; ++r) {
        int o = wm * 144 + mf * 16 + quad * 4 + r;
        float v = acc[mf][nf][r] + b1[o];
        if (o < 256) qo[((size_t)b * C + o) * HW + n] = (f16)v;
        else         kvo[((size_t)b * DH + (o - 256)) * HW + n] = v;
      }
    }
  }
}

// ============================================================================
// K2: per-kv-row softmax stats over 4096 positions. 512 rows, 1 wave each.
// ============================================================================
__global__ __launch_bounds__(64) void k2_stats(
    const float* __restrict__ kv, float* __restrict__ rowmax, float* __restrict__ rowsum) {
  int r = blockIdx.x, lane = threadIdx.x;
  const float* row = kv + (size_t)r * HW;
  float m = -1e30f;
  for (int i = 0; i < 64; ++i) m = fmaxf(m, row[lane + i * 64]);
  for (int off = 32; off; off >>= 1) m = fmaxf(m, __shfl_xor(m, off));
  float s = 0.f;
  for (int i = 0; i < 64; ++i) s += __expf(row[lane + i * 64] - m);
  for (int off = 32; off; off >>= 1) s += __shfl_xor(s, off);
  if (lane == 0) { rowmax[r] = m; rowsum[r] = s; }
}

// ============================================================================
// K3: ctx_t[b][d][e] = sum_n softmaxrow_e(kv)[n] * kv[d][n]  (1/S_e folded in)
// grid (16 spatial chunks, 16 batches), block 256. atomicAdd into U.
// ============================================================================
__global__ __launch_bounds__(256) void k3_ctx(
    const float* __restrict__ kv, const float* __restrict__ rowmax,
    const float* __restrict__ rowsum, float* __restrict__ U) {
  __shared__ alignas(16) float kvc[256 * 36];  // [n][d], pitch 36
  __shared__ alignas(16) float wc [256 * 36];  // [n][e] softmaxed, pitch 36

  const int t = threadIdx.x;
  const int b = blockIdx.y;
  const int n0 = blockIdx.x * 256;

  for (int idx = t; idx < 32 * 64; idx += 256) {
    int r = idx & 31, nq = idx >> 5;  // row, n-quad
    const float4 v = *(const float4*)&kv[((size_t)b * DH + r) * HW + n0 + nq * 4];
    float M = rowmax[b * DH + r];
    float Sinv = 1.f / rowsum[b * DH + r];
    int n = nq * 4;
    kvc[(n + 0) * 36 + r] = v.x;  wc[(n + 0) * 36 + r] = __expf(v.x - M) * Sinv;
    kvc[(n + 1) * 36 + r] = v.y;  wc[(n + 1) * 36 + r] = __expf(v.y - M) * Sinv;
    kvc[(n + 2) * 36 + r] = v.z;  wc[(n + 2) * 36 + r] = __expf(v.z - M) * Sinv;
    kvc[(n + 3) * 36 + r] = v.w;  wc[(n + 3) * 36 + r] = __expf(v.w - M) * Sinv;
  }
  __syncthreads();

  const int d = t & 31, eg = t >> 5;
  float a0 = 0, a1 = 0, a2 = 0, a3 = 0;
  for (int n = 0; n < 256; ++n) {
    float kd = kvc[n * 36 + d];
    const float4 w4 = *(const float4*)&wc[n * 36 + eg * 4];
    a0 += w4.x * kd; a1 += w4.y * kd; a2 += w4.z * kd; a3 += w4.w * kd;
  }
  float* Ub = U + b * 1024 + d * 32 + eg * 4;
  atomicAdd(Ub + 0, a0); atomicAdd(Ub + 1, a1);
  atomicAdd(Ub + 2, a2); atomicAdd(Ub + 3, a3);
}

// ============================================================================
// K4: fused channel-softmax + per-head ctx*p (MFMA) + ReLU + proj GEMM (MFMA).
// Block = (batch, 32 positions). out(256x32) = Wp'(256x256) * att(256x32).
// ============================================================================
__global__ __launch_bounds__(256) void k4_attproj(
    const f16* __restrict__ qg, const float* __restrict__ U,
    const f16* __restrict__ Wp2, const float* __restrict__ bp2, float* __restrict__ out) {
  __shared__ alignas(16) f16 qa[256 * 40];   // q tile [c][n] pitch 40; later aliased as att_t[n][c] pitch 264
  __shared__ alignas(16) f16 pt[32 * 264];   // softmax probs [n][c] pitch 264
  __shared__ alignas(16) f16 ctxs[32 * 32];  // ctx_t [d][e]
  __shared__ alignas(16) f16 Wpa[256 * 40];  // Wp' K-chunk [256][32] pitch 40

  const int t = threadIdx.x;
  const int b = blockIdx.y;
  const int n0 = blockIdx.x * 32;
  const int lane = t & 63, w = t >> 6;
  const int l15 = lane & 15, quad = lane >> 4;

  // stage ctx (f32 -> f16)
  {
    const float4 u4 = *(const float4*)&U[b * 1024 + t * 4];
    f16x4 pk = { (f16)u4.x, (f16)u4.y, (f16)u4.z, (f16)u4.w };
    *(f16x4*)&ctxs[t * 4] = pk;
  }
  // stage q tile [c][n0..n0+31]
  for (int it = 0; it < 8; ++it) {
    int c = it * 32 + (t >> 3), seg = t & 7;
    *(f16x4*)&qa[c * 40 + seg * 4] = *(const f16x4*)&qg[((size_t)b * C + c) * HW + n0 + seg * 4];
  }
  __syncthreads();

  // channel softmax: task (n, h) over 32 channels
  {
    int n = t & 31, h = t >> 5;
    float vals[32];
    float m = -1e30f;
#pragma unroll
    for (int e = 0; e < 32; ++e) {
      float v = (float)qa[(h * 32 + e) * 40 + n];
      vals[e] = v; m = fmaxf(m, v);
    }
    float s = 0.f;
#pragma unroll
    for (int e = 0; e < 32; ++e) { float p = __expf(vals[e] - m); vals[e] = p; s += p; }
    float sinv = 1.f / s;
#pragma unroll
    for (int g = 0; g < 8; ++g) {
      f16x4 pk = { (f16)(vals[g * 4 + 0] * sinv), (f16)(vals[g * 4 + 1] * sinv),
                   (f16)(vals[g * 4 + 2] * sinv), (f16)(vals[g * 4 + 3] * sinv) };
      *(f16x4*)&pt[n * 264 + h * 32 + g * 4] = pk;
    }
  }
  __syncthreads();

  // att = ctx_t * p per head (wave w handles heads 2w, 2w+1), ReLU -> att_t (alias qa)
  f32x4 attacc[2][2][2];
  const f32x4 zf = { 0.f, 0.f, 0.f, 0.f };
#pragma unroll
  for (int hh = 0; hh < 2; ++hh) {
    int h = w * 2 + hh;
#pragma unroll
    for (int mt = 0; mt < 2; ++mt) {
      f16x8 af = *(const f16x8*)&ctxs[(mt * 16 + l15) * 32 + quad * 8];
#pragma unroll
      for (int nt = 0; nt < 2; ++nt) {
        f16x8 bf = *(const f16x8*)&pt[(nt * 16 + l15) * 264 + h * 32 + quad * 8];
        attacc[hh][mt][nt] = MFMA16(af, bf, zf);
      }
    }
  }
  __syncthreads();  // everyone done reading qa (softmax phase) long ago; safe to overwrite via alias
#pragma unroll
  for (int hh = 0; hh < 2; ++hh) {
    int h = w * 2 + hh;
#pragma unroll
    for (int mt = 0; mt < 2; ++mt) {
#pragma unroll
      for (int nt = 0; nt < 2; ++nt) {
        int n = nt * 16 + l15;
        int cb = h * 32 + mt * 16 + quad * 4;
        f32x4 v = attacc[hh][mt][nt];
        f16x4 pk = { (f16)fmaxf(v[0], 0.f), (f16)fmaxf(v[1], 0.f),
                     (f16)fmaxf(v[2], 0.f), (f16)fmaxf(v[3], 0.f) };
        *(f16x4*)&qa[n * 264 + cb] = pk;  // att_t[n][c] pitch 264 (aliased buffer)
      }
    }
  }

  // proj GEMM: waves 2x2 over (M-half=128, N-half=16)
  const int wm = w & 1, wn = w >> 1;
  f32x4 acc[8] = {};
  for (int kc = 0; kc < 8; ++kc) {
    __syncthreads();
    for (int u = t; u < 1024; u += 256) {
      int r = u >> 2, s = u & 3;
      *(f16x8*)&Wpa[r * 40 + s * 8] = *(const f16x8*)&Wp2[r * 256 + kc * 32 + s * 8];
    }
    __syncthreads();
    f16x8 bf = *(const f16x8*)&qa[(wn * 16 + l15) * 264 + kc * 32 + quad * 8];
#pragma unroll
    for (int mf = 0; mf < 8; ++mf) {
      f16x8 af = *(const f16x8*)&Wpa[(wm * 128 + mf * 16 + l15) * 40 + quad * 8];
      acc[mf] = MFMA16(af, bf, acc[mf]);
    }
  }

  // epilogue: +bias, store fp32
#pragma unroll
  for (int mf = 0; mf < 8; ++mf) {
    int n = n0 + wn * 16 + l15;
#pragma unroll
    for (int r = 0; r < 4; ++r) {
      int o = wm * 128 + mf * 16 + quad * 4 + r;
      out[((size_t)b * C + o) * HW + n] = acc[mf][r] + bp2[o];
    }
  }
}

// ============================================================================
extern "C" void kernel_launch(void* const* d_in, const int* in_sizes, int n_in,
                              void* d_out, int out_size, void* d_ws, size_t ws_size,
                              hipStream_t stream) {
  (void)in_sizes; (void)n_in; (void)out_size; (void)ws_size;
  const float* input = (const float*)d_in[0];
  // d_in[1] (key_v_input_reduction) is unused by the reference.
  const float* Wq  = (const float*)d_in[2];
  const float* gq  = (const float*)d_in[3];
  const float* bq  = (const float*)d_in[4];
  const float* mq  = (const float*)d_in[5];
  const float* vq  = (const float*)d_in[6];
  const float* Wkv = (const float*)d_in[7];
  const float* gkv = (const float*)d_in[8];
  const float* bkv = (const float*)d_in[9];
  const float* mkv = (const float*)d_in[10];
  const float* vkv = (const float*)d_in[11];
  const float* Wp  = (const float*)d_in[12];
  const float* gp  = (const float*)d_in[13];
  const float* bp  = (const float*)d_in[14];
  const float* mp  = (const float*)d_in[15];
  const float* vp  = (const float*)d_in[16];

  char* ws = (char*)d_ws;
  f16*   qw  = (f16*)(ws + OFF_Q);
  float* kvw = (float*)(ws + OFF_KV);
  f16*   W1  = (f16*)(ws + OFF_W1);
  float* b1  = (float*)(ws + OFF_B1);
  f16*   Wp2 = (f16*)(ws + OFF_WP);
  float* bp2 = (float*)(ws + OFF_BP);
  float* rm  = (float*)(ws + OFF_RM);
  float* rs  = (float*)(ws + OFF_RS);
  float* U   = (float*)(ws + OFF_U);
  float* out = (float*)d_out;

  hipMemsetAsync(U, 0, (size_t)BATCH * DH * DH * 4, stream);
  k0_prep<<<547, 256, 0, stream>>>(Wq, gq, bq, mq, vq, Wkv, gkv, bkv, mkv, vkv,
                                   Wp, gp, bp, mp, vp, W1, b1, Wp2, bp2);
  k1_qkv<<<dim3(64, 16), 256, 0, stream>>>(input, W1, b1, qw, kvw);
  k2_stats<<<512, 64, 0, stream>>>(kvw, rm, rs);
  k3_ctx<<<dim3(16, 16), 256, 0, stream>>>(kvw, rm, rs, U);
  k4_attproj<<<dim3(128, 16), 256, 0, stream>>>(qw, U, Wp2, bp2, out);
}

// Round 2
// 252.814 us; speedup vs baseline: 1.0538x; 1.0538x over previous
//
#include <hip/hip_runtime.h>
#include <hip/hip_bf16.h>
#include <cstdint>

typedef _Float16 f16;
typedef _Float16 f16x4 __attribute__((ext_vector_type(4)));
typedef _Float16 f16x8 __attribute__((ext_vector_type(8)));
typedef float f32x4 __attribute__((ext_vector_type(4)));

#define MFMA16(a, b, c) __builtin_amdgcn_mfma_f32_16x16x32_f16((a), (b), (c), 0, 0, 0)

constexpr int BATCH = 16;
constexpr int C     = 256;    // dim
constexpr int HW    = 4096;   // 64*64 spatial
constexpr int DH    = 32;     // qkv_dim
constexpr int MR    = 288;    // 256 q rows + 32 kv rows in fused QKV GEMM
constexpr float EPS = 1e-5f;

// ---- workspace layout (bytes) ----
constexpr size_t OFF_Q  = 0;                                   // f16 [16][256][4096]
constexpr size_t SZ_Q   = (size_t)BATCH * C * HW * 2;
constexpr size_t OFF_KV = OFF_Q + SZ_Q;                        // f32 [16][32][4096]
constexpr size_t SZ_KV  = (size_t)BATCH * DH * HW * 4;
constexpr size_t OFF_W1 = OFF_KV + SZ_KV;                      // f16 [288][256] (BN inv folded)
constexpr size_t SZ_W1  = (size_t)MR * C * 2;
constexpr size_t OFF_B1 = OFF_W1 + SZ_W1;                      // f32 [288]
constexpr size_t OFF_WP = OFF_B1 + 2048;                       // f16 [256][256]
constexpr size_t SZ_WP  = (size_t)C * C * 2;
constexpr size_t OFF_BP = OFF_WP + SZ_WP;                      // f32 [256]
constexpr size_t OFF_RM = OFF_BP + 1024;                       // f32 [512] row max
constexpr size_t OFF_RS = OFF_RM + 2048;                       // f32 [512] row expsum
constexpr size_t OFF_U  = OFF_RS + 2048;                       // f32 [16][32][32] ctx_t
constexpr size_t WS_NEED = OFF_U + (size_t)BATCH * DH * DH * 4; // ~40.4 MB

// ============================================================================
// K0: fold BN (gamma/sqrt(var+eps)) into conv weights; f16 weights, f32 biases
// ============================================================================
__global__ __launch_bounds__(256) void k0_prep(
    const float* __restrict__ Wq,  const float* __restrict__ gq,  const float* __restrict__ bq,
    const float* __restrict__ mq,  const float* __restrict__ vq,
    const float* __restrict__ Wkv, const float* __restrict__ gkv, const float* __restrict__ bkv,
    const float* __restrict__ mkv, const float* __restrict__ vkv,
    const float* __restrict__ Wp,  const float* __restrict__ gp,  const float* __restrict__ bp,
    const float* __restrict__ mp,  const float* __restrict__ vp,
    f16* __restrict__ W1, float* __restrict__ b1, f16* __restrict__ Wp2, float* __restrict__ bp2) {
  int id = blockIdx.x * 256 + threadIdx.x;
  if (id < 65536) {                       // Wq' rows 0..255
    int o = id >> 8, c = id & 255;
    float inv = gq[o] * rsqrtf(vq[o] + EPS);
    W1[o * 256 + c] = (f16)(Wq[o * 256 + c] * inv);
  } else if (id < 73728) {                // Wkv' rows 256..287
    int o = (id - 65536) >> 8, c = id & 255;
    float inv = gkv[o] * rsqrtf(vkv[o] + EPS);
    W1[(256 + o) * 256 + c] = (f16)(Wkv[o * 256 + c] * inv);
  } else if (id < 139264) {               // Wp'
    int o = (id - 73728) >> 8, c = id & 255;
    float inv = gp[o] * rsqrtf(vp[o] + EPS);
    Wp2[o * 256 + c] = (f16)(Wp[o * 256 + c] * inv);
  } else if (id < 139552) {               // bias for QKV GEMM
    int r = id - 139264;
    if (r < 256) { float inv = gq[r] * rsqrtf(vq[r] + EPS);   b1[r] = bq[r] - mq[r] * inv; }
    else { int e = r - 256; float inv = gkv[e] * rsqrtf(vkv[e] + EPS); b1[r] = bkv[e] - mkv[e] * inv; }
  } else if (id < 139808) {               // bias for proj
    int o = id - 139552;
    float inv = gp[o] * rsqrtf(vp[o] + EPS);
    bp2[o] = bp[o] - mp[o] * inv;
  }
}

// ============================================================================
// K1: fused QKV projection. Per batch: D(288x4096) = W1(288x256) * X(256x4096)
// A (W1) streamed DIRECTLY from global (L2-hot, no LDS staging / no A barrier).
// B (X^T chunk) register-transposed into double-buffered LDS: 1 barrier per kc,
// next chunk's global loads issued before the MFMAs so latency hides behind MFMA.
// ============================================================================
__global__ __launch_bounds__(256) void k1_qkv(
    const float* __restrict__ X, const f16* __restrict__ W1, const float* __restrict__ b1,
    f16* __restrict__ qo, float* __restrict__ kvo) {
  __shared__ alignas(16) f16 Bt[2][64 * 40];   // X^T chunk [n=64][k=32], pitch 40 f16

  const int t = threadIdx.x;
  const int n0 = blockIdx.x * 64;
  const int b  = blockIdx.y;
  const float* Xb = X + (size_t)b * C * HW;

  const int lane = t & 63, w = t >> 6;
  const int l15 = lane & 15, quad = lane >> 4;
  const int wm = w & 1, wn = w >> 1;

  const int xn = t & 63, cg = t >> 6;  // transpose task: column n, channel-group of 8

  float xr[8];
  auto loadX = [&](int kc) {
    const float* Xc = Xb + (size_t)(kc * 32 + cg * 8) * HW + n0 + xn;
#pragma unroll
    for (int j = 0; j < 8; ++j) xr[j] = Xc[(size_t)j * HW];
  };
  auto storeB = [&](int bu) {
    f16x4 p0 = { (f16)xr[0], (f16)xr[1], (f16)xr[2], (f16)xr[3] };
    f16x4 p1 = { (f16)xr[4], (f16)xr[5], (f16)xr[6], (f16)xr[7] };
    *(f16x4*)&Bt[bu][xn * 40 + cg * 8]     = p0;
    *(f16x4*)&Bt[bu][xn * 40 + cg * 8 + 4] = p1;
  };

  f32x4 acc[9][2] = {};

  loadX(0); storeB(0); __syncthreads();
  int p = 0;
  for (int kc = 0; kc < 8; ++kc) {
    if (kc < 7) loadX(kc + 1);  // in-flight across the MFMAs below
    f16x8 bf0 = *(const f16x8*)&Bt[p][(wn * 32 + l15) * 40 + quad * 8];
    f16x8 bf1 = *(const f16x8*)&Bt[p][(wn * 32 + 16 + l15) * 40 + quad * 8];
#pragma unroll
    for (int mf = 0; mf < 9; ++mf) {
      f16x8 af = *(const f16x8*)&W1[(wm * 144 + mf * 16 + l15) * 256 + kc * 32 + quad * 8];
      acc[mf][0] = MFMA16(af, bf0, acc[mf][0]);
      acc[mf][1] = MFMA16(af, bf1, acc[mf][1]);
    }
    if (kc < 7) storeB(p ^ 1);
    __syncthreads();
    p ^= 1;
  }

  // epilogue: +bias, split q (f16) / kv (f32)
#pragma unroll
  for (int mf = 0; mf < 9; ++mf) {
#pragma unroll
    for (int nf = 0; nf < 2; ++nf) {
      int n = n0 + wn * 32 + nf * 16 + l15;
#pragma unroll
      for (int r = 0; r < 4; ++r) {
        int o = wm * 144 + mf * 16 + quad * 4 + r;
        float v = acc[mf][nf][r] + b1[o];
        if (o < 256) qo[((size_t)b * C + o) * HW + n] = (f16)v;
        else         kvo[((size_t)b * DH + (o - 256)) * HW + n] = v;
      }
    }
  }
}

// ============================================================================
// K2: per-kv-row softmax stats. One 256-thr block per row; whole row lives in
// registers (16 floats/lane) -> single global pass for max AND exp-sum.
// ============================================================================
__global__ __launch_bounds__(256) void k2_stats(
    const float* __restrict__ kv, float* __restrict__ rowmax, float* __restrict__ rowsum) {
  int r = blockIdx.x, t = threadIdx.x, w = t >> 6, lane = t & 63;
  const float4* row = (const float4*)(kv + (size_t)r * HW);
  float4 v0 = row[t], v1 = row[t + 256], v2 = row[t + 512], v3 = row[t + 768];
  float m = fmaxf(fmaxf(fmaxf(v0.x, v0.y), fmaxf(v0.z, v0.w)),
                  fmaxf(fmaxf(v1.x, v1.y), fmaxf(v1.z, v1.w)));
  m = fmaxf(m, fmaxf(fmaxf(fmaxf(v2.x, v2.y), fmaxf(v2.z, v2.w)),
                     fmaxf(fmaxf(v3.x, v3.y), fmaxf(v3.z, v3.w))));
  for (int off = 32; off; off >>= 1) m = fmaxf(m, __shfl_xor(m, off));
  __shared__ float sm[4], ss[4];
  if (lane == 0) sm[w] = m;
  __syncthreads();
  m = fmaxf(fmaxf(sm[0], sm[1]), fmaxf(sm[2], sm[3]));
  float s = __expf(v0.x - m) + __expf(v0.y - m) + __expf(v0.z - m) + __expf(v0.w - m)
          + __expf(v1.x - m) + __expf(v1.y - m) + __expf(v1.z - m) + __expf(v1.w - m)
          + __expf(v2.x - m) + __expf(v2.y - m) + __expf(v2.z - m) + __expf(v2.w - m)
          + __expf(v3.x - m) + __expf(v3.y - m) + __expf(v3.z - m) + __expf(v3.w - m);
  for (int off = 32; off; off >>= 1) s += __shfl_xor(s, off);
  if (lane == 0) ss[w] = s;
  __syncthreads();
  if (t == 0) { rowmax[r] = m; rowsum[r] = ss[0] + ss[1] + ss[2] + ss[3]; }
}

// ============================================================================
// K3: ctx_t[b][d][e] = sum_n softmaxrow_e(kv)[n] * kv[d][n]  (1/S_e folded in)
// grid (16 spatial chunks, 16 batches), block 256. atomicAdd into U.
// ============================================================================
__global__ __launch_bounds__(256) void k3_ctx(
    const float* __restrict__ kv, const float* __restrict__ rowmax,
    const float* __restrict__ rowsum, float* __restrict__ U) {
  __shared__ alignas(16) float kvc[256 * 36];  // [n][d], pitch 36
  __shared__ alignas(16) float wc [256 * 36];  // [n][e] softmaxed, pitch 36

  const int t = threadIdx.x;
  const int b = blockIdx.y;
  const int n0 = blockIdx.x * 256;

  for (int idx = t; idx < 32 * 64; idx += 256) {
    int r = idx & 31, nq = idx >> 5;  // row, n-quad
    const float4 v = *(const float4*)&kv[((size_t)b * DH + r) * HW + n0 + nq * 4];
    float M = rowmax[b * DH + r];
    float Sinv = 1.f / rowsum[b * DH + r];
    int n = nq * 4;
    kvc[(n + 0) * 36 + r] = v.x;  wc[(n + 0) * 36 + r] = __expf(v.x - M) * Sinv;
    kvc[(n + 1) * 36 + r] = v.y;  wc[(n + 1) * 36 + r] = __expf(v.y - M) * Sinv;
    kvc[(n + 2) * 36 + r] = v.z;  wc[(n + 2) * 36 + r] = __expf(v.z - M) * Sinv;
    kvc[(n + 3) * 36 + r] = v.w;  wc[(n + 3) * 36 + r] = __expf(v.w - M) * Sinv;
  }
  __syncthreads();

  const int d = t & 31, eg = t >> 5;
  float a0 = 0, a1 = 0, a2 = 0, a3 = 0;
  for (int n = 0; n < 256; ++n) {
    float kd = kvc[n * 36 + d];
    const float4 w4 = *(const float4*)&wc[n * 36 + eg * 4];
    a0 += w4.x * kd; a1 += w4.y * kd; a2 += w4.z * kd; a3 += w4.w * kd;
  }
  float* Ub = U + b * 1024 + d * 32 + eg * 4;
  atomicAdd(Ub + 0, a0); atomicAdd(Ub + 1, a1);
  atomicAdd(Ub + 2, a2); atomicAdd(Ub + 3, a3);
}

// ============================================================================
// K4: fused channel-softmax + per-head ctx*p (MFMA) + ReLU + proj GEMM (MFMA).
// Ntile=64 positions. Proj A-operand (Wp') streamed directly from global (L2):
// the whole proj K-loop is barrier-free. 3 barriers total per block.
// ============================================================================
__global__ __launch_bounds__(256) void k4_attproj(
    const f16* __restrict__ qg, const float* __restrict__ U,
    const f16* __restrict__ Wp2, const float* __restrict__ bp2, float* __restrict__ out) {
  __shared__ alignas(16) f16 qa[256 * 72];   // q [c][n=64] pitch 72; aliased later as att_t[n=64][c] pitch 264 (16896 <= 18432)
  __shared__ alignas(16) f16 pt[64 * 264];   // softmax probs [n][c] pitch 264
  __shared__ alignas(16) f16 ctxs[32 * 32];  // ctx_t [d][e]

  const int t = threadIdx.x;
  const int b = blockIdx.y;
  const int n0 = blockIdx.x * 64;
  const int lane = t & 63, w = t >> 6;
  const int l15 = lane & 15, quad = lane >> 4;

  // stage ctx (f32 -> f16)
  {
    const float4 u4 = *(const float4*)&U[b * 1024 + t * 4];
    f16x4 pk = { (f16)u4.x, (f16)u4.y, (f16)u4.z, (f16)u4.w };
    *(f16x4*)&ctxs[t * 4] = pk;
  }
  // stage q tile [c][n0..n0+63], f16x8 units
#pragma unroll
  for (int it = 0; it < 8; ++it) {
    int u = t + it * 256, c = u >> 3, seg = u & 7;
    *(f16x8*)&qa[c * 72 + seg * 8] = *(const f16x8*)&qg[((size_t)b * C + c) * HW + n0 + seg * 8];
  }
  __syncthreads();

  // channel softmax: 512 tasks (n, h), 2 per thread
#pragma unroll
  for (int it = 0; it < 2; ++it) {
    int id = t + it * 256, n = id & 63, h = id >> 6;
    float vals[32];
    float m = -1e30f;
#pragma unroll
    for (int e = 0; e < 32; ++e) {
      float v = (float)qa[(h * 32 + e) * 72 + n];
      vals[e] = v; m = fmaxf(m, v);
    }
    float s = 0.f;
#pragma unroll
    for (int e = 0; e < 32; ++e) { float pr = __expf(vals[e] - m); vals[e] = pr; s += pr; }
    float sinv = 1.f / s;
#pragma unroll
    for (int g = 0; g < 8; ++g) {
      f16x4 pk = { (f16)(vals[g * 4 + 0] * sinv), (f16)(vals[g * 4 + 1] * sinv),
                   (f16)(vals[g * 4 + 2] * sinv), (f16)(vals[g * 4 + 3] * sinv) };
      *(f16x4*)&pt[n * 264 + h * 32 + g * 4] = pk;
    }
  }
  __syncthreads();

  // att = ctx_t * p per head (wave w -> heads 2w, 2w+1), ReLU -> att_t (alias qa)
  f32x4 attacc[2][2][4];
  const f32x4 zf = { 0.f, 0.f, 0.f, 0.f };
#pragma unroll
  for (int hh = 0; hh < 2; ++hh) {
    int h = w * 2 + hh;
#pragma unroll
    for (int mt = 0; mt < 2; ++mt) {
      f16x8 af = *(const f16x8*)&ctxs[(mt * 16 + l15) * 32 + quad * 8];
#pragma unroll
      for (int nt = 0; nt < 4; ++nt) {
        f16x8 bf = *(const f16x8*)&pt[(nt * 16 + l15) * 264 + h * 32 + quad * 8];
        attacc[hh][mt][nt] = MFMA16(af, bf, zf);
      }
    }
  }
#pragma unroll
  for (int hh = 0; hh < 2; ++hh) {
    int h = w * 2 + hh;
#pragma unroll
    for (int mt = 0; mt < 2; ++mt) {
#pragma unroll
      for (int nt = 0; nt < 4; ++nt) {
        int n = nt * 16 + l15;
        int cb = h * 32 + mt * 16 + quad * 4;
        f32x4 v = attacc[hh][mt][nt];
        f16x4 pk = { (f16)fmaxf(v[0], 0.f), (f16)fmaxf(v[1], 0.f),
                     (f16)fmaxf(v[2], 0.f), (f16)fmaxf(v[3], 0.f) };
        *(f16x4*)&qa[n * 264 + cb] = pk;  // att_t[n][c] pitch 264 (aliased buffer)
      }
    }
  }
  __syncthreads();

  // proj GEMM: waves 2x2 over (M-half=128, N-half=32); A from global, barrier-free
  const int wm = w & 1, wn = w >> 1;
  f32x4 acc[8][2] = {};
#pragma unroll
  for (int kc = 0; kc < 8; ++kc) {
    f16x8 bf0 = *(const f16x8*)&qa[(wn * 32 + l15) * 264 + kc * 32 + quad * 8];
    f16x8 bf1 = *(const f16x8*)&qa[(wn * 32 + 16 + l15) * 264 + kc * 32 + quad * 8];
#pragma unroll
    for (int mf = 0; mf < 8; ++mf) {
      f16x8 af = *(const f16x8*)&Wp2[(wm * 128 + mf * 16 + l15) * 256 + kc * 32 + quad * 8];
      acc[mf][0] = MFMA16(af, bf0, acc[mf][0]);
      acc[mf][1] = MFMA16(af, bf1, acc[mf][1]);
    }
  }

  // epilogue: +bias, store fp32
#pragma unroll
  for (int mf = 0; mf < 8; ++mf) {
#pragma unroll
    for (int nf = 0; nf < 2; ++nf) {
      int n = n0 + wn * 32 + nf * 16 + l15;
#pragma unroll
      for (int r = 0; r < 4; ++r) {
        int o = wm * 128 + mf * 16 + quad * 4 + r;
        out[((size_t)b * C + o) * HW + n] = acc[mf][nf][r] + bp2[o];
      }
    }
  }
}

// ============================================================================
extern "C" void kernel_launch(void* const* d_in, const int* in_sizes, int n_in,
                              void* d_out, int out_size, void* d_ws, size_t ws_size,
                              hipStream_t stream) {
  (void)in_sizes; (void)n_in; (void)out_size; (void)ws_size;
  const float* input = (const float*)d_in[0];
  // d_in[1] (key_v_input_reduction) is unused by the reference.
  const float* Wq  = (const float*)d_in[2];
  const float* gq  = (const float*)d_in[3];
  const float* bq  = (const float*)d_in[4];
  const float* mq  = (const float*)d_in[5];
  const float* vq  = (const float*)d_in[6];
  const float* Wkv = (const float*)d_in[7];
  const float* gkv = (const float*)d_in[8];
  const float* bkv = (const float*)d_in[9];
  const float* mkv = (const float*)d_in[10];
  const float* vkv = (const float*)d_in[11];
  const float* Wp  = (const float*)d_in[12];
  const float* gp  = (const float*)d_in[13];
  const float* bp  = (const float*)d_in[14];
  const float* mp  = (const float*)d_in[15];
  const float* vp  = (const float*)d_in[16];

  char* ws = (char*)d_ws;
  f16*   qw  = (f16*)(ws + OFF_Q);
  float* kvw = (float*)(ws + OFF_KV);
  f16*   W1  = (f16*)(ws + OFF_W1);
  float* b1  = (float*)(ws + OFF_B1);
  f16*   Wp2 = (f16*)(ws + OFF_WP);
  float* bp2 = (float*)(ws + OFF_BP);
  float* rm  = (float*)(ws + OFF_RM);
  float* rs  = (float*)(ws + OFF_RS);
  float* U   = (float*)(ws + OFF_U);
  float* out = (float*)d_out;

  hipMemsetAsync(U, 0, (size_t)BATCH * DH * DH * 4, stream);
  k0_prep<<<547, 256, 0, stream>>>(Wq, gq, bq, mq, vq, Wkv, gkv, bkv, mkv, vkv,
                                   Wp, gp, bp, mp, vp, W1, b1, Wp2, bp2);
  k1_qkv<<<dim3(64, 16), 256, 0, stream>>>(input, W1, b1, qw, kvw);
  k2_stats<<<512, 256, 0, stream>>>(kvw, rm, rs);
  k3_ctx<<<dim3(16, 16), 256, 0, stream>>>(kvw, rm, rs, U);
  k4_attproj<<<dim3(64, 16), 256, 0, stream>>>(qw, U, Wp2, bp2, out);
}